// Round 1
// baseline (94.786 us; speedup 1.0000x reference)
//
#include <hip/hip_runtime.h>

// ContextNorm: row-wise mean/std(ddof=1) normalize, then elementwise scale+bias.
// X: [B=65536, D=1024] f32; weights: [D] f32; bias: [D] f32; out: [B, D] f32.
//
// One wave (64 lanes) per row: 1024 cols / 64 lanes = 16 f32 = 4x float4 per lane.
// Lane-interleaved float4 accesses -> fully coalesced 1KB/instruction per wave.
// Wave-level shfl_xor reduction; no LDS, no barriers.

#define DIM 1024
#define ROWS_PER_BLOCK 4  // 4 waves/block * 1 row/wave

__global__ __launch_bounds__(256) void contextnorm_kernel(
    const float* __restrict__ X,
    const float* __restrict__ W,
    const float* __restrict__ Bv,
    float* __restrict__ out,
    int batch) {

    const int wave = threadIdx.x >> 6;   // 0..3
    const int lane = threadIdx.x & 63;
    const int row  = blockIdx.x * ROWS_PER_BLOCK + wave;
    if (row >= batch) return;

    const float4* __restrict__ xr = reinterpret_cast<const float4*>(X + (size_t)row * DIM);
    float4* __restrict__ orow     = reinterpret_cast<float4*>(out + (size_t)row * DIM);
    const float4* __restrict__ w4 = reinterpret_cast<const float4*>(W);
    const float4* __restrict__ b4 = reinterpret_cast<const float4*>(Bv);

    float4 v[4];
    float sum = 0.0f, sq = 0.0f;
    #pragma unroll
    for (int c = 0; c < 4; ++c) {
        v[c] = xr[c * 64 + lane];
        sum += v[c].x + v[c].y + v[c].z + v[c].w;
        sq  += v[c].x * v[c].x + v[c].y * v[c].y + v[c].z * v[c].z + v[c].w * v[c].w;
    }

    // 64-lane butterfly reduction (wave = 64 on CDNA).
    #pragma unroll
    for (int off = 32; off >= 1; off >>= 1) {
        sum += __shfl_xor(sum, off, 64);
        sq  += __shfl_xor(sq,  off, 64);
    }

    const float mean = sum * (1.0f / DIM);
    // unbiased variance (ddof=1): (sumsq - N*mean^2) / (N-1)
    float var = (sq - (float)DIM * mean * mean) * (1.0f / (DIM - 1));
    var = fmaxf(var, 0.0f);
    const float inv = 1.0f / sqrtf(var);

    #pragma unroll
    for (int c = 0; c < 4; ++c) {
        const float4 wv = w4[c * 64 + lane];
        const float4 bb = b4[c * 64 + lane];
        float4 o;
        o.x = (v[c].x - mean) * inv * wv.x + bb.x;
        o.y = (v[c].y - mean) * inv * wv.y + bb.y;
        o.z = (v[c].z - mean) * inv * wv.z + bb.z;
        o.w = (v[c].w - mean) * inv * wv.w + bb.w;
        orow[c * 64 + lane] = o;
    }
}

extern "C" void kernel_launch(void* const* d_in, const int* in_sizes, int n_in,
                              void* d_out, int out_size, void* d_ws, size_t ws_size,
                              hipStream_t stream) {
    const float* X  = (const float*)d_in[0];
    const float* W  = (const float*)d_in[1];
    const float* Bv = (const float*)d_in[2];
    float* out = (float*)d_out;

    const int dim = in_sizes[1];        // 1024
    const int batch = in_sizes[0] / dim; // 65536
    (void)dim;

    const int grid = (batch + ROWS_PER_BLOCK - 1) / ROWS_PER_BLOCK;
    contextnorm_kernel<<<grid, 256, 0, stream>>>(X, W, Bv, out, batch);
}

// Round 3
// 90.986 us; speedup vs baseline: 1.0418x; 1.0418x over previous
//
#include <hip/hip_runtime.h>

// ContextNorm: row-wise mean/std(ddof=1) normalize, then elementwise scale+bias.
// X: [B=65536, D=1024] f32; weights: [D] f32; bias: [D] f32; out: [B, D] f32.
//
// One wave (64 lanes) per row: 1024 cols / 64 lanes = 16 f32 = 4x float4 per lane.
// Lane-interleaved float4 accesses -> fully coalesced 1KB/instruction per wave.
// Wave-level shfl_xor reduction; no LDS, no barriers.
// Round 3: nontemporal load/store via clang ext_vector float4 (HIP's float4 is
// a struct and is rejected by __builtin_nontemporal_*).

#define DIM 1024
#define ROWS_PER_BLOCK 4  // 4 waves/block * 1 row/wave

typedef float f4 __attribute__((ext_vector_type(4)));

__global__ __launch_bounds__(256) void contextnorm_kernel(
    const float* __restrict__ X,
    const float* __restrict__ W,
    const float* __restrict__ Bv,
    float* __restrict__ out,
    int batch) {

    const int wave = threadIdx.x >> 6;   // 0..3
    const int lane = threadIdx.x & 63;
    const int row  = blockIdx.x * ROWS_PER_BLOCK + wave;
    if (row >= batch) return;

    const f4* __restrict__ xr = reinterpret_cast<const f4*>(X + (size_t)row * DIM);
    f4* __restrict__ orow     = reinterpret_cast<f4*>(out + (size_t)row * DIM);
    const f4* __restrict__ w4 = reinterpret_cast<const f4*>(W);
    const f4* __restrict__ b4 = reinterpret_cast<const f4*>(Bv);

    f4 v[4];
    float sum = 0.0f, sq = 0.0f;
    #pragma unroll
    for (int c = 0; c < 4; ++c) {
        v[c] = __builtin_nontemporal_load(&xr[c * 64 + lane]);
        sum += v[c].x + v[c].y + v[c].z + v[c].w;
        sq  += v[c].x * v[c].x + v[c].y * v[c].y + v[c].z * v[c].z + v[c].w * v[c].w;
    }

    // 64-lane butterfly reduction (wave = 64 on CDNA).
    #pragma unroll
    for (int off = 32; off >= 1; off >>= 1) {
        sum += __shfl_xor(sum, off, 64);
        sq  += __shfl_xor(sq,  off, 64);
    }

    const float mean = sum * (1.0f / DIM);
    // unbiased variance (ddof=1): (sumsq - N*mean^2) / (N-1)
    float var = (sq - (float)DIM * mean * mean) * (1.0f / (DIM - 1));
    var = fmaxf(var, 0.0f);
    const float inv = 1.0f / sqrtf(var);

    #pragma unroll
    for (int c = 0; c < 4; ++c) {
        const f4 wv = w4[c * 64 + lane];
        const f4 bb = b4[c * 64 + lane];
        f4 o;
        o.x = (v[c].x - mean) * inv * wv.x + bb.x;
        o.y = (v[c].y - mean) * inv * wv.y + bb.y;
        o.z = (v[c].z - mean) * inv * wv.z + bb.z;
        o.w = (v[c].w - mean) * inv * wv.w + bb.w;
        __builtin_nontemporal_store(o, &orow[c * 64 + lane]);
    }
}

extern "C" void kernel_launch(void* const* d_in, const int* in_sizes, int n_in,
                              void* d_out, int out_size, void* d_ws, size_t ws_size,
                              hipStream_t stream) {
    const float* X  = (const float*)d_in[0];
    const float* W  = (const float*)d_in[1];
    const float* Bv = (const float*)d_in[2];
    float* out = (float*)d_out;

    const int dim = in_sizes[1];        // 1024
    const int batch = in_sizes[0] / dim; // 65536
    (void)dim;

    const int grid = (batch + ROWS_PER_BLOCK - 1) / ROWS_PER_BLOCK;
    contextnorm_kernel<<<grid, 256, 0, stream>>>(X, W, Bv, out, batch);
}